// Round 1
// baseline (4067.750 us; speedup 1.0000x reference)
//
#include <hip/hip_runtime.h>
#include <cfloat>
#include <cmath>

#define B_ 1024
#define D_ 256
#define H_ 512
#define N_ 100000
#define K_ 96
#define C_ 10

// ---------------------------------------------------------------------------
// Generic fp32 tiled GEMM: C = act(A[M,Kd] @ Bm[Kd,N] + bias)
// 64x64 block tile, BK=16, 256 threads, 4x4 per-thread microtile.
// A staged transposed in LDS so fragments read as float4.
// ---------------------------------------------------------------------------
template <int RELU>
__global__ __launch_bounds__(256) void gemm_nn(const float* __restrict__ A,
                                               const float* __restrict__ Bm,
                                               const float* __restrict__ bias,
                                               float* __restrict__ Cm,
                                               int M, int N, int Kd) {
    __shared__ float sA[16][68];   // [k][m], pad 68 -> 272B stride (16B aligned)
    __shared__ float sB[16][64];   // [k][n]
    const int t  = threadIdx.x;
    const int tx = t & 15, ty = t >> 4;
    const int m0 = blockIdx.y * 64;
    const int n0 = blockIdx.x * 64;
    const int lr = t >> 2;           // 0..63  A row
    const int lk = (t & 3) << 2;     // 0,4,8,12
    const int bk = t >> 4;           // 0..15  B row (k)
    const int bn = (t & 15) << 2;    // 0..60  B col

    float acc[4][4] = {};
    for (int k0 = 0; k0 < Kd; k0 += 16) {
        float4 av = make_float4(0.f, 0.f, 0.f, 0.f);
        if (m0 + lr < M)
            av = *(const float4*)(A + (size_t)(m0 + lr) * Kd + k0 + lk);
        sA[lk + 0][lr] = av.x; sA[lk + 1][lr] = av.y;
        sA[lk + 2][lr] = av.z; sA[lk + 3][lr] = av.w;
        float4 bv = *(const float4*)(Bm + (size_t)(k0 + bk) * N + n0 + bn);
        *(float4*)&sB[bk][bn] = bv;
        __syncthreads();
#pragma unroll
        for (int kk = 0; kk < 16; ++kk) {
            float4 a4 = *(const float4*)&sA[kk][ty << 2];
            float4 b4 = *(const float4*)&sB[kk][tx << 2];
            float ar[4] = {a4.x, a4.y, a4.z, a4.w};
            float br[4] = {b4.x, b4.y, b4.z, b4.w};
#pragma unroll
            for (int i = 0; i < 4; ++i)
#pragma unroll
                for (int j = 0; j < 4; ++j)
                    acc[i][j] = fmaf(ar[i], br[j], acc[i][j]);
        }
        __syncthreads();
    }
#pragma unroll
    for (int i = 0; i < 4; ++i) {
        int row = m0 + (ty << 2) + i;
        if (row < M) {
            int col = n0 + (tx << 2);
            float b0 = 0.f, b1 = 0.f, b2 = 0.f, b3 = 0.f;
            if (bias) { b0 = bias[col]; b1 = bias[col + 1]; b2 = bias[col + 2]; b3 = bias[col + 3]; }
            float4 o;
            o.x = acc[i][0] + b0; o.y = acc[i][1] + b1;
            o.z = acc[i][2] + b2; o.w = acc[i][3] + b3;
            if (RELU) {
                o.x = fmaxf(o.x, 0.f); o.y = fmaxf(o.y, 0.f);
                o.z = fmaxf(o.z, 0.f); o.w = fmaxf(o.w, 0.f);
            }
            *(float4*)(Cm + (size_t)row * N + col) = o;
        }
    }
}

// ---------------------------------------------------------------------------
// NT GEMM for similarities: S[b][jb] = -sqrt(max(q2[b]+c2[j]-2*dot(xk_b,ck_j),0))
// ---------------------------------------------------------------------------
__global__ __launch_bounds__(256) void gemm_sim(const float* __restrict__ XK,
                                                const float* __restrict__ CK,
                                                const float* __restrict__ q2,
                                                const float* __restrict__ c2,
                                                float* __restrict__ S,
                                                int j0, int ncols, int ldc) {
    __shared__ float sA[16][68];
    __shared__ float sBt[16][68];
    const int t  = threadIdx.x;
    const int tx = t & 15, ty = t >> 4;
    const int m0 = blockIdx.y * 64;
    const int jb = blockIdx.x * 64;
    const int lr = t >> 2;
    const int lk = (t & 3) << 2;

    float acc[4][4] = {};
    for (int k0 = 0; k0 < H_; k0 += 16) {
        float4 av = *(const float4*)(XK + (size_t)(m0 + lr) * H_ + k0 + lk);
        sA[lk + 0][lr] = av.x; sA[lk + 1][lr] = av.y;
        sA[lk + 2][lr] = av.z; sA[lk + 3][lr] = av.w;
        int jrow = j0 + jb + lr;
        float4 bv = make_float4(0.f, 0.f, 0.f, 0.f);
        if (jrow < N_)
            bv = *(const float4*)(CK + (size_t)jrow * H_ + k0 + lk);
        sBt[lk + 0][lr] = bv.x; sBt[lk + 1][lr] = bv.y;
        sBt[lk + 2][lr] = bv.z; sBt[lk + 3][lr] = bv.w;
        __syncthreads();
#pragma unroll
        for (int kk = 0; kk < 16; ++kk) {
            float4 a4 = *(const float4*)&sA[kk][ty << 2];
            float4 b4 = *(const float4*)&sBt[kk][tx << 2];
            float ar[4] = {a4.x, a4.y, a4.z, a4.w};
            float br[4] = {b4.x, b4.y, b4.z, b4.w};
#pragma unroll
            for (int i = 0; i < 4; ++i)
#pragma unroll
                for (int j = 0; j < 4; ++j)
                    acc[i][j] = fmaf(ar[i], br[j], acc[i][j]);
        }
        __syncthreads();
    }
#pragma unroll
    for (int i = 0; i < 4; ++i) {
        int row = m0 + (ty << 2) + i;   // always < B_
        float qq = q2[row];
#pragma unroll
        for (int j = 0; j < 4; ++j) {
            int col = jb + (tx << 2) + j;
            if (col < ncols) {
                int jg = j0 + col;
                float d2 = qq + c2[jg] - 2.f * acc[i][j];
                d2 = fmaxf(d2, 0.f);
                S[(size_t)row * ldc + col] = -sqrtf(d2);
            }
        }
    }
}

// ---------------------------------------------------------------------------
// Streaming top-96 merge. One block per query row. Threshold filter into LDS
// buffer; bitonic-sort flush (2048 wide) keeps top 96 + updates threshold.
// ---------------------------------------------------------------------------
#define TK_SORT 2048
#define TK_TOP  96
#define TK_CAP  (TK_SORT - TK_TOP)   // 1952
#define TK_SEG  1024

__device__ __forceinline__ void tk_flush(float* sv, int* si, int* nbuf,
                                         float* sthr, int t) {
    int n = *nbuf;  // uniform: last writes synced before call
    for (int s = TK_TOP + n + t; s < TK_SORT; s += 256) {
        sv[s] = -FLT_MAX; si[s] = -1;
    }
    __syncthreads();
    for (int k = 2; k <= TK_SORT; k <<= 1) {
        for (int j = k >> 1; j > 0; j >>= 1) {
            for (int x = t; x < TK_SORT; x += 256) {
                int ixj = x ^ j;
                if (ixj > x) {
                    bool up = ((x & k) == 0);     // descending order
                    float v1 = sv[x], v2 = sv[ixj];
                    if (up ? (v1 < v2) : (v1 > v2)) {
                        sv[x] = v2; sv[ixj] = v1;
                        int tmp = si[x]; si[x] = si[ixj]; si[ixj] = tmp;
                    }
                }
            }
            __syncthreads();
        }
    }
    if (t == 0) { *nbuf = 0; *sthr = sv[TK_TOP - 1]; }
    __syncthreads();
}

__global__ __launch_bounds__(256) void topk_merge(const float* __restrict__ S,
                                                  int ldc, int ncols, int j0,
                                                  float* __restrict__ topVal,
                                                  int* __restrict__ topIdx,
                                                  float* __restrict__ thrArr) {
    __shared__ float sv[TK_SORT];
    __shared__ int   si[TK_SORT];
    __shared__ int   nbuf;
    __shared__ float sthr;
    const int b = blockIdx.x;
    const int t = threadIdx.x;
    for (int i = t; i < TK_TOP; i += 256) {
        sv[i] = topVal[b * TK_TOP + i];
        si[i] = topIdx[b * TK_TOP + i];
    }
    if (t == 0) { nbuf = 0; sthr = thrArr[b]; }
    __syncthreads();
    const float* row = S + (size_t)b * ldc;
    for (int seg = 0; seg < ncols; seg += TK_SEG) {
        if (nbuf + TK_SEG > TK_CAP) tk_flush(sv, si, &nbuf, &sthr, t);
        float thr = sthr;
        int end = min(seg + TK_SEG, ncols);
        for (int i = seg + t; i < end; i += 256) {
            float v = row[i];
            if (v > thr) {
                int p = atomicAdd(&nbuf, 1);
                sv[TK_TOP + p] = v;
                si[TK_TOP + p] = j0 + i;
            }
        }
        __syncthreads();
    }
    if (nbuf > 0) tk_flush(sv, si, &nbuf, &sthr, t);
    for (int i = t; i < TK_TOP; i += 256) {
        topVal[b * TK_TOP + i] = sv[i];
        topIdx[b * TK_TOP + i] = si[i];
    }
    if (t == 0) thrArr[b] = sv[TK_TOP - 1];
}

__global__ void topk_init(float* topVal, int* topIdx, float* thrArr) {
    int i = blockIdx.x * 256 + threadIdx.x;
    if (i < B_ * K_) { topVal[i] = -FLT_MAX; topIdx[i] = 0; }
    if (i < B_) thrArr[i] = -FLT_MAX;
}

// ---------------------------------------------------------------------------
__global__ __launch_bounds__(128) void softmax_k(const float* __restrict__ topVal,
                                                 float* __restrict__ attn) {
    __shared__ float red[128];
    const int b = blockIdx.x, t = threadIdx.x;
    float v = (t < K_) ? topVal[b * K_ + t] : -FLT_MAX;
    red[t] = v; __syncthreads();
    for (int s = 64; s > 0; s >>= 1) {
        if (t < s) red[t] = fmaxf(red[t], red[t + s]);
        __syncthreads();
    }
    float m = red[0]; __syncthreads();
    float e = (t < K_) ? expf(v - m) : 0.f;
    red[t] = e; __syncthreads();
    for (int s = 64; s > 0; s >>= 1) {
        if (t < s) red[t] += red[t + s];
        __syncthreads();
    }
    float ssum = red[0];
    if (t < K_) attn[b * K_ + t] = e / ssum;
}

__global__ __launch_bounds__(128) void gather_diff(const float* __restrict__ XK,
                                                   const float* __restrict__ CK,
                                                   const int* __restrict__ topI,
                                                   float* __restrict__ diff,
                                                   int b0) {
    const int r = blockIdx.x;            // local row within chunk
    const int b = b0 + r / K_;
    const int idx = topI[b * K_ + (r % K_)];
    const int t = threadIdx.x;
    float4 xv = *(const float4*)(XK + (size_t)b * H_ + t * 4);
    float4 cv = *(const float4*)(CK + (size_t)idx * H_ + t * 4);
    float4 o = make_float4(xv.x - cv.x, xv.y - cv.y, xv.z - cv.z, xv.w - cv.w);
    *(float4*)(diff + (size_t)r * H_ + t * 4) = o;
}

__global__ __launch_bounds__(256) void reduce_ctx(const float* __restrict__ attn,
                                                  const int* __restrict__ topI,
                                                  const int* __restrict__ labels,
                                                  const float* __restrict__ E,
                                                  const float* __restrict__ tout,
                                                  const float* __restrict__ xe,
                                                  float* __restrict__ out, int b0) {
    const int bl = blockIdx.x;
    const int b = b0 + bl;
    const int t = threadIdx.x;
    float a0 = 0.f, a1 = 0.f;
    for (int k = 0; k < K_; ++k) {
        float w = attn[b * K_ + k];
        int idx = topI[b * K_ + k];
        int lab = labels[idx];
        const float* el = E + (size_t)lab * H_;
        const float* tr = tout + (size_t)(bl * K_ + k) * H_;
        a0 = fmaf(w, el[t] + tr[t], a0);
        a1 = fmaf(w, el[t + 256] + tr[t + 256], a1);
    }
    out[(size_t)b * H_ + t]       = xe[(size_t)b * H_ + t] + a0;
    out[(size_t)b * H_ + t + 256] = xe[(size_t)b * H_ + t + 256] + a1;
}

__global__ __launch_bounds__(64) void rowsq(const float* __restrict__ X,
                                            float* __restrict__ outv) {
    const int r = blockIdx.x;
    const int t = threadIdx.x;
    const float* p = X + (size_t)r * H_;
    float4 a = *(const float4*)(p + t * 4);
    float4 b = *(const float4*)(p + 256 + t * 4);
    float v = a.x * a.x + a.y * a.y + a.z * a.z + a.w * a.w +
              b.x * b.x + b.y * b.y + b.z * b.z + b.w * b.w;
    for (int off = 32; off > 0; off >>= 1) v += __shfl_down(v, off);
    if (t == 0) outv[r] = v;
}

__global__ void bcomb_k(const float* __restrict__ b_enc,
                        const float* __restrict__ W_key,
                        const float* __restrict__ b_key,
                        float* __restrict__ b_comb) {
    int h = blockIdx.x * 256 + threadIdx.x;
    if (h >= H_) return;
    float acc = b_key[h];
    for (int m = 0; m < H_; ++m)
        acc = fmaf(b_enc[m], W_key[(size_t)m * H_ + h], acc);
    b_comb[h] = acc;
}

// ---------------------------------------------------------------------------
extern "C" void kernel_launch(void* const* d_in, const int* in_sizes, int n_in,
                              void* d_out, int out_size, void* d_ws, size_t ws_size,
                              hipStream_t stream) {
    const float* x      = (const float*)d_in[0];
    const float* cx     = (const float*)d_in[1];
    const int*   labels = (const int*)d_in[2];
    const float* W_enc  = (const float*)d_in[3];
    const float* b_enc  = (const float*)d_in[4];
    const float* W_key  = (const float*)d_in[5];
    const float* b_key  = (const float*)d_in[6];
    // d_in[7]=W_val, d_in[8]=b_val : dead code in reference (gather unused)
    const float* E_label = (const float*)d_in[9];
    const float* W_t1   = (const float*)d_in[10];
    const float* b_t1   = (const float*)d_in[11];
    const float* W_t2   = (const float*)d_in[12];
    float* out = (float*)d_out;

    char* base = (char*)d_ws;
    size_t off = 0;
    auto take = [&](size_t n) -> char* {
        char* p = base + off;
        off = (off + n + 255) & ~(size_t)255;
        return p;
    };
    float* Wc   = (float*)take((size_t)D_ * H_ * 4);
    float* bc   = (float*)take((size_t)H_ * 4);
    float* xe   = (float*)take((size_t)B_ * H_ * 4);
    float* xk   = (float*)take((size_t)B_ * H_ * 4);
    float* q2   = (float*)take((size_t)B_ * 4);
    float* ck   = (float*)take((size_t)N_ * H_ * 4);
    float* c2   = (float*)take((size_t)N_ * 4);
    float* topV = (float*)take((size_t)B_ * K_ * 4);
    int*   topI = (int*)take((size_t)B_ * K_ * 4);
    float* thr  = (float*)take((size_t)B_ * 4);
    float* attn = (float*)take((size_t)B_ * K_ * 4);
    char*  big  = base + off;
    size_t rem = (ws_size > off) ? (ws_size - off) : 0;

    // sim chunk width (cols), multiple of 64
    size_t perCol = (size_t)B_ * 4;
    long long nc = (long long)((rem / perCol) & ~(size_t)63);
    if (nc > ((N_ + 63) / 64) * 64) nc = ((N_ + 63) / 64) * 64;
    if (nc < 64) nc = 64;
    int Nc0 = (int)nc;
    // T-MLP chunk (queries per pass): needs 2 * Bc*96*512*4 bytes
    long long bcq = (long long)(rem / ((size_t)K_ * H_ * 4 * 2));
    if (bcq > B_) bcq = B_;
    if (bcq < 1) bcq = 1;
    int Bc = (int)bcq;

    // --- stage 0: combined weights ---
    {
        dim3 g(H_ / 64, D_ / 64);
        gemm_nn<0><<<g, 256, 0, stream>>>(W_enc, W_key, nullptr, Wc, D_, H_, H_);
        bcomb_k<<<(H_ + 255) / 256, 256, 0, stream>>>(b_enc, W_key, b_key, bc);
    }
    // --- stage 1: encode queries + candidates ---
    {
        dim3 gx(H_ / 64, B_ / 64);
        gemm_nn<0><<<gx, 256, 0, stream>>>(x, W_enc, b_enc, xe, B_, H_, D_);
        gemm_nn<0><<<gx, 256, 0, stream>>>(x, Wc, bc, xk, B_, H_, D_);
        dim3 gc(H_ / 64, (N_ + 63) / 64);
        gemm_nn<0><<<gc, 256, 0, stream>>>(cx, Wc, bc, ck, N_, H_, D_);
        rowsq<<<N_, 64, 0, stream>>>(ck, c2);
        rowsq<<<B_, 64, 0, stream>>>(xk, q2);
    }
    // --- stage 2: chunked sim GEMM + streaming top-k ---
    topk_init<<<(B_ * K_ + 255) / 256, 256, 0, stream>>>(topV, topI, thr);
    float* simBuf = (float*)big;
    for (int j0 = 0; j0 < N_; j0 += Nc0) {
        int ncols = min(Nc0, N_ - j0);
        dim3 g((ncols + 63) / 64, B_ / 64);
        gemm_sim<<<g, 256, 0, stream>>>(xk, ck, q2, c2, simBuf, j0, ncols, Nc0);
        topk_merge<<<B_, 256, 0, stream>>>(simBuf, Nc0, ncols, j0, topV, topI, thr);
    }
    // --- stage 3: attention weights ---
    softmax_k<<<B_, 128, 0, stream>>>(topV, attn);
    // --- stage 4: correction MLP + weighted reduction, chunked over queries ---
    float* diffBuf = (float*)big;  // reused as t_out after GEMM1 consumes it
    float* hBuf = (float*)(big + (size_t)Bc * K_ * H_ * 4);
    for (int b0 = 0; b0 < B_; b0 += Bc) {
        int bcn = min(Bc, B_ - b0);
        int Mrows = bcn * K_;
        gather_diff<<<Mrows, 128, 0, stream>>>(xk, ck, topI, diffBuf, b0);
        dim3 g1(H_ / 64, (Mrows + 63) / 64);
        gemm_nn<1><<<g1, 256, 0, stream>>>(diffBuf, W_t1, b_t1, hBuf, Mrows, H_, H_);
        gemm_nn<0><<<g1, 256, 0, stream>>>(hBuf, W_t2, nullptr, diffBuf, Mrows, H_, H_);
        reduce_ctx<<<bcn, 256, 0, stream>>>(attn, topI, labels, E_label, diffBuf, xe, out, b0);
    }
}

// Round 2
// 1505.418 us; speedup vs baseline: 2.7021x; 2.7021x over previous
//
#include <hip/hip_runtime.h>
#include <cfloat>
#include <cmath>

#define B_ 1024
#define D_ 256
#define H_ 512
#define N_ 100000
#define K_ 96
#define C_ 10

typedef __attribute__((ext_vector_type(8))) short bf16x8;
typedef __attribute__((ext_vector_type(4))) float f32x4;

__device__ __forceinline__ float bf2f(ushort h) {
    union { unsigned u; float f; } v; v.u = ((unsigned)h) << 16; return v.f;
}
__device__ __forceinline__ ushort f2bf(float f) {
    union { float f; unsigned u; } v; v.f = f;
    unsigned u = v.u;
    unsigned r = (u + 0x7fffu + ((u >> 16) & 1u)) >> 16;
    return (ushort)r;
}

#define GLDS(g, l)                                                            \
    __builtin_amdgcn_global_load_lds(                                         \
        (const __attribute__((address_space(1))) void*)(g),                   \
        (__attribute__((address_space(3))) void*)(l), 16, 0, 0)

// ---------------------------------------------------------------------------
// fp32 tiled GEMM (round-1, kept for tiny fp32 GEMMs: Wc, xe, xk)
// ---------------------------------------------------------------------------
template <int RELU>
__global__ __launch_bounds__(256) void gemm_nn(const float* __restrict__ A,
                                               const float* __restrict__ Bm,
                                               const float* __restrict__ bias,
                                               float* __restrict__ Cm,
                                               int M, int N, int Kd) {
    __shared__ float sA[16][68];
    __shared__ float sB[16][64];
    const int t  = threadIdx.x;
    const int tx = t & 15, ty = t >> 4;
    const int m0 = blockIdx.y * 64;
    const int n0 = blockIdx.x * 64;
    const int lr = t >> 2;
    const int lk = (t & 3) << 2;
    const int bk = t >> 4;
    const int bn = (t & 15) << 2;

    float acc[4][4] = {};
    for (int k0 = 0; k0 < Kd; k0 += 16) {
        float4 av = make_float4(0.f, 0.f, 0.f, 0.f);
        if (m0 + lr < M)
            av = *(const float4*)(A + (size_t)(m0 + lr) * Kd + k0 + lk);
        sA[lk + 0][lr] = av.x; sA[lk + 1][lr] = av.y;
        sA[lk + 2][lr] = av.z; sA[lk + 3][lr] = av.w;
        float4 bv = *(const float4*)(Bm + (size_t)(k0 + bk) * N + n0 + bn);
        *(float4*)&sB[bk][bn] = bv;
        __syncthreads();
#pragma unroll
        for (int kk = 0; kk < 16; ++kk) {
            float4 a4 = *(const float4*)&sA[kk][ty << 2];
            float4 b4 = *(const float4*)&sB[kk][tx << 2];
            float ar[4] = {a4.x, a4.y, a4.z, a4.w};
            float br[4] = {b4.x, b4.y, b4.z, b4.w};
#pragma unroll
            for (int i = 0; i < 4; ++i)
#pragma unroll
                for (int j = 0; j < 4; ++j)
                    acc[i][j] = fmaf(ar[i], br[j], acc[i][j]);
        }
        __syncthreads();
    }
#pragma unroll
    for (int i = 0; i < 4; ++i) {
        int row = m0 + (ty << 2) + i;
        if (row < M) {
            int col = n0 + (tx << 2);
            float b0 = 0.f, b1 = 0.f, b2 = 0.f, b3 = 0.f;
            if (bias) { b0 = bias[col]; b1 = bias[col + 1]; b2 = bias[col + 2]; b3 = bias[col + 3]; }
            float4 o;
            o.x = acc[i][0] + b0; o.y = acc[i][1] + b1;
            o.z = acc[i][2] + b2; o.w = acc[i][3] + b3;
            if (RELU) {
                o.x = fmaxf(o.x, 0.f); o.y = fmaxf(o.y, 0.f);
                o.z = fmaxf(o.z, 0.f); o.w = fmaxf(o.w, 0.f);
            }
            *(float4*)(Cm + (size_t)row * N + col) = o;
        }
    }
}

// ---------------------------------------------------------------------------
// bf16 MFMA NT GEMM: C = epilogue(A[M,K] @ B[N,K]^T)
// 128x128 tile, BK=32, 4 waves, each 4x4 tiles of 16x16x32 MFMA.
// m97 recipe: global_load_lds width 16 into un-padded row-major LDS.
// MODE 0: out bf16               MODE 1: +bias, relu, out bf16
// MODE 2: sim -sqrt(max(q2+c2-2acc,0)) out fp32
// MODE 3: +bias (no relu), out bf16
// ---------------------------------------------------------------------------
template <int MODE>
__global__ __launch_bounds__(256) void gemm_nt(const ushort* __restrict__ A,
                                               const ushort* __restrict__ Bv,
                                               const float* __restrict__ bias,
                                               const float* __restrict__ q2v,
                                               const float* __restrict__ c2v,
                                               void* __restrict__ Cout,
                                               int M, int Nlim, int K,
                                               int ldc, int nvalid) {
    __shared__ ushort sA[128 * 32];
    __shared__ ushort sB[128 * 32];
    const int t = threadIdx.x;
    const int lane = t & 63, w = t >> 6;
    const int wm = w & 1, wn = w >> 1;
    const int m0 = blockIdx.y * 128, n0 = blockIdx.x * 128;

    f32x4 acc[4][4];
#pragma unroll
    for (int i = 0; i < 4; ++i)
#pragma unroll
        for (int j = 0; j < 4; ++j)
            acc[i][j] = (f32x4){0.f, 0.f, 0.f, 0.f};

    const int la = lane & 15, lk = lane >> 4;
    const int aoff = (wm * 64 + la) * 64 + lk * 16;  // bytes; + i*1024
    const int boff = (wn * 64 + la) * 64 + lk * 16;  // bytes; + j*1024
    const int r_ = t >> 2, cc_ = (t & 3);

    for (int k0 = 0; k0 < K; k0 += 32) {
#pragma unroll
        for (int q = 0; q < 2; ++q) {
            int r = r_ + q * 64;
            int ar = m0 + r; ar = (ar < M) ? ar : (M - 1);
            GLDS(A + (size_t)ar * K + k0 + cc_ * 8, (char*)sA + (q * 256 + t) * 16);
            int br = n0 + r; br = (br < Nlim) ? br : (Nlim - 1);
            GLDS(Bv + (size_t)br * K + k0 + cc_ * 8, (char*)sB + (q * 256 + t) * 16);
        }
        __syncthreads();
        bf16x8 af[4], bfr[4];
#pragma unroll
        for (int i = 0; i < 4; ++i)
            af[i] = *(const bf16x8*)((const char*)sA + aoff + i * 1024);
#pragma unroll
        for (int j = 0; j < 4; ++j)
            bfr[j] = *(const bf16x8*)((const char*)sB + boff + j * 1024);
#pragma unroll
        for (int i = 0; i < 4; ++i)
#pragma unroll
            for (int j = 0; j < 4; ++j)
                acc[i][j] = __builtin_amdgcn_mfma_f32_16x16x32_bf16(
                    af[i], bfr[j], acc[i][j], 0, 0, 0);
        __syncthreads();
    }

    const int rl = (lane >> 4) * 4, cl = lane & 15;
#pragma unroll
    for (int i = 0; i < 4; ++i) {
#pragma unroll
        for (int j = 0; j < 4; ++j) {
            int gc = n0 + wn * 64 + j * 16 + cl;
#pragma unroll
            for (int v = 0; v < 4; ++v) {
                int gr = m0 + wm * 64 + i * 16 + rl + v;
                if (gr < M && gc < nvalid) {
                    float val = acc[i][j][v];
                    if (MODE == 2) {
                        float d2 = q2v[gr] + c2v[gc] - 2.f * val;
                        ((float*)Cout)[(size_t)gr * ldc + gc] = -sqrtf(fmaxf(d2, 0.f));
                    } else {
                        if (MODE == 1 || MODE == 3) val += bias[gc];
                        if (MODE == 1) val = fmaxf(val, 0.f);
                        ((ushort*)Cout)[(size_t)gr * ldc + gc] = f2bf(val);
                    }
                }
            }
        }
    }
}

// ---------------------------------------------------------------------------
__global__ void conv_f2b(const float* __restrict__ in, ushort* __restrict__ out, int n) {
    int i = (blockIdx.x * 256 + threadIdx.x) * 4;
    int stride = gridDim.x * 256 * 4;
    for (; i < n; i += stride) {
        float4 v = *(const float4*)(in + i);
        ushort4 o;
        o.x = f2bf(v.x); o.y = f2bf(v.y); o.z = f2bf(v.z); o.w = f2bf(v.w);
        *(ushort4*)(out + i) = o;
    }
}

__global__ __launch_bounds__(256) void transpose_f2b(const float* __restrict__ in,
                                                     ushort* __restrict__ out,
                                                     int R, int Cn) {
    __shared__ float tile[32][33];
    int bx = blockIdx.x * 32, by = blockIdx.y * 32;
    int tx = threadIdx.x & 31, ty = threadIdx.x >> 5;   // 32 x 8
    int x = bx + tx;
#pragma unroll
    for (int dy = 0; dy < 32; dy += 8) {
        int y = by + ty + dy;
        if (x < Cn && y < R) tile[ty + dy][tx] = in[(size_t)y * Cn + x];
    }
    __syncthreads();
    int ox = by + tx;
#pragma unroll
    for (int dy = 0; dy < 32; dy += 8) {
        int oy = bx + ty + dy;
        if (ox < R && oy < Cn) out[(size_t)oy * R + ox] = f2bf(tile[tx][ty + dy]);
    }
}

__global__ __launch_bounds__(64) void rowsq_b(const ushort* __restrict__ X,
                                              float* __restrict__ outv) {
    const int r = blockIdx.x, t = threadIdx.x;
    const ushort* p = X + (size_t)r * H_;
    ushort4 a = *(const ushort4*)(p + t * 4);
    ushort4 b = *(const ushort4*)(p + 256 + t * 4);
    float ax = bf2f(a.x), ay = bf2f(a.y), az = bf2f(a.z), aw = bf2f(a.w);
    float bx = bf2f(b.x), by = bf2f(b.y), bz = bf2f(b.z), bw = bf2f(b.w);
    float v = ax * ax + ay * ay + az * az + aw * aw +
              bx * bx + by * by + bz * bz + bw * bw;
    for (int off = 32; off > 0; off >>= 1) v += __shfl_down(v, off);
    if (t == 0) outv[r] = v;
}

__global__ void bcomb_k(const float* __restrict__ b_enc,
                        const float* __restrict__ W_key,
                        const float* __restrict__ b_key,
                        float* __restrict__ b_comb) {
    int h = blockIdx.x * 256 + threadIdx.x;
    if (h >= H_) return;
    float acc = b_key[h];
    for (int m = 0; m < H_; ++m)
        acc = fmaf(b_enc[m], W_key[(size_t)m * H_ + h], acc);
    b_comb[h] = acc;
}

// ---------------------------------------------------------------------------
#define TK_SORT 2048
#define TK_TOP  96
#define TK_CAP  (TK_SORT - TK_TOP)
#define TK_SEG  1024

__device__ __forceinline__ void tk_flush(float* sv, int* si, int* nbuf,
                                         float* sthr, int t) {
    int n = *nbuf;
    for (int s = TK_TOP + n + t; s < TK_SORT; s += 256) {
        sv[s] = -FLT_MAX; si[s] = -1;
    }
    __syncthreads();
    for (int k = 2; k <= TK_SORT; k <<= 1) {
        for (int j = k >> 1; j > 0; j >>= 1) {
            for (int x = t; x < TK_SORT; x += 256) {
                int ixj = x ^ j;
                if (ixj > x) {
                    bool up = ((x & k) == 0);
                    float v1 = sv[x], v2 = sv[ixj];
                    if (up ? (v1 < v2) : (v1 > v2)) {
                        sv[x] = v2; sv[ixj] = v1;
                        int tmp = si[x]; si[x] = si[ixj]; si[ixj] = tmp;
                    }
                }
            }
            __syncthreads();
        }
    }
    if (t == 0) { *nbuf = 0; *sthr = sv[TK_TOP - 1]; }
    __syncthreads();
}

__global__ __launch_bounds__(256) void topk_merge(const float* __restrict__ S,
                                                  int ldc, int ncols, int j0,
                                                  float* __restrict__ topVal,
                                                  int* __restrict__ topIdx,
                                                  float* __restrict__ thrArr) {
    __shared__ float sv[TK_SORT];
    __shared__ int   si[TK_SORT];
    __shared__ int   nbuf;
    __shared__ float sthr;
    const int b = blockIdx.x;
    const int t = threadIdx.x;
    for (int i = t; i < TK_TOP; i += 256) {
        sv[i] = topVal[b * TK_TOP + i];
        si[i] = topIdx[b * TK_TOP + i];
    }
    if (t == 0) { nbuf = 0; sthr = thrArr[b]; }
    __syncthreads();
    const float* row = S + (size_t)b * ldc;
    for (int seg = 0; seg < ncols; seg += TK_SEG) {
        if (nbuf + TK_SEG > TK_CAP) tk_flush(sv, si, &nbuf, &sthr, t);
        float thr = sthr;
        int end = min(seg + TK_SEG, ncols);
        for (int i = seg + t; i < end; i += 256) {
            float v = row[i];
            if (v > thr) {
                int p = atomicAdd(&nbuf, 1);
                sv[TK_TOP + p] = v;
                si[TK_TOP + p] = j0 + i;
            }
        }
        __syncthreads();
    }
    if (nbuf > 0) tk_flush(sv, si, &nbuf, &sthr, t);
    for (int i = t; i < TK_TOP; i += 256) {
        topVal[b * TK_TOP + i] = sv[i];
        topIdx[b * TK_TOP + i] = si[i];
    }
    if (t == 0) thrArr[b] = sv[TK_TOP - 1];
}

__global__ void topk_init(float* topVal, int* topIdx, float* thrArr) {
    int i = blockIdx.x * 256 + threadIdx.x;
    if (i < B_ * K_) { topVal[i] = -FLT_MAX; topIdx[i] = 0; }
    if (i < B_) thrArr[i] = -FLT_MAX;
}

__global__ __launch_bounds__(128) void softmax_k(const float* __restrict__ topVal,
                                                 float* __restrict__ attn) {
    __shared__ float red[128];
    const int b = blockIdx.x, t = threadIdx.x;
    float v = (t < K_) ? topVal[b * K_ + t] : -FLT_MAX;
    red[t] = v; __syncthreads();
    for (int s = 64; s > 0; s >>= 1) {
        if (t < s) red[t] = fmaxf(red[t], red[t + s]);
        __syncthreads();
    }
    float m = red[0]; __syncthreads();
    float e = (t < K_) ? expf(v - m) : 0.f;
    red[t] = e; __syncthreads();
    for (int s = 64; s > 0; s >>= 1) {
        if (t < s) red[t] += red[t + s];
        __syncthreads();
    }
    float ssum = red[0];
    if (t < K_) attn[b * K_ + t] = e / ssum;
}

__global__ __launch_bounds__(128) void gather_diff_b(const float* __restrict__ XK,
                                                     const ushort* __restrict__ CK,
                                                     const int* __restrict__ topI,
                                                     ushort* __restrict__ diff,
                                                     int b0) {
    const int r = blockIdx.x;
    const int b = b0 + r / K_;
    const int idx = topI[b * K_ + (r % K_)];
    const int t = threadIdx.x;
    float4 xv = *(const float4*)(XK + (size_t)b * H_ + t * 4);
    ushort4 cv = *(const ushort4*)(CK + (size_t)idx * H_ + t * 4);
    ushort4 o;
    o.x = f2bf(xv.x - bf2f(cv.x));
    o.y = f2bf(xv.y - bf2f(cv.y));
    o.z = f2bf(xv.z - bf2f(cv.z));
    o.w = f2bf(xv.w - bf2f(cv.w));
    *(ushort4*)(diff + (size_t)r * H_ + t * 4) = o;
}

__global__ __launch_bounds__(256) void reduce_ctx(const float* __restrict__ attn,
                                                  const int* __restrict__ topI,
                                                  const int* __restrict__ labels,
                                                  const float* __restrict__ E,
                                                  const ushort* __restrict__ tout,
                                                  const float* __restrict__ xe,
                                                  float* __restrict__ out, int b0) {
    const int bl = blockIdx.x;
    const int b = b0 + bl;
    const int t = threadIdx.x;
    float a0 = 0.f, a1 = 0.f;
    for (int k = 0; k < K_; ++k) {
        float w = attn[b * K_ + k];
        int idx = topI[b * K_ + k];
        int lab = labels[idx];
        const float* el = E + (size_t)lab * H_;
        const ushort* tr = tout + (size_t)(bl * K_ + k) * H_;
        a0 = fmaf(w, el[t] + bf2f(tr[t]), a0);
        a1 = fmaf(w, el[t + 256] + bf2f(tr[t + 256]), a1);
    }
    out[(size_t)b * H_ + t]       = xe[(size_t)b * H_ + t] + a0;
    out[(size_t)b * H_ + t + 256] = xe[(size_t)b * H_ + t + 256] + a1;
}

// ---------------------------------------------------------------------------
extern "C" void kernel_launch(void* const* d_in, const int* in_sizes, int n_in,
                              void* d_out, int out_size, void* d_ws, size_t ws_size,
                              hipStream_t stream) {
    const float* x      = (const float*)d_in[0];
    const float* cx     = (const float*)d_in[1];
    const int*   labels = (const int*)d_in[2];
    const float* W_enc  = (const float*)d_in[3];
    const float* b_enc  = (const float*)d_in[4];
    const float* W_key  = (const float*)d_in[5];
    const float* b_key  = (const float*)d_in[6];
    // d_in[7]=W_val, d_in[8]=b_val dead (gather unused in reference)
    const float* E_label = (const float*)d_in[9];
    const float* W_t1   = (const float*)d_in[10];
    const float* b_t1   = (const float*)d_in[11];
    const float* W_t2   = (const float*)d_in[12];
    float* out = (float*)d_out;

    char* base = (char*)d_ws;
    size_t off = 0;
    auto take = [&](size_t n) -> char* {
        char* p = base + off;
        off = (off + n + 255) & ~(size_t)255;
        return p;
    };
    float*  Wc    = (float*)take((size_t)D_ * H_ * 4);
    float*  bc    = (float*)take((size_t)H_ * 4);
    ushort* WcT   = (ushort*)take((size_t)H_ * D_ * 2);
    ushort* Wt1T  = (ushort*)take((size_t)H_ * H_ * 2);
    ushort* Wt2T  = (ushort*)take((size_t)H_ * H_ * 2);
    float*  xe    = (float*)take((size_t)B_ * H_ * 4);
    float*  xk    = (float*)take((size_t)B_ * H_ * 4);
    ushort* xkb   = (ushort*)take((size_t)B_ * H_ * 2);
    float*  q2    = (float*)take((size_t)B_ * 4);
    ushort* cxb   = (ushort*)take((size_t)N_ * D_ * 2);
    ushort* ckb   = (ushort*)take((size_t)N_ * H_ * 2);
    float*  c2    = (float*)take((size_t)N_ * 4);
    float*  topV  = (float*)take((size_t)B_ * K_ * 4);
    int*    topI  = (int*)take((size_t)B_ * K_ * 4);
    float*  thr   = (float*)take((size_t)B_ * 4);
    float*  attn  = (float*)take((size_t)B_ * K_ * 4);
    char*   big   = base + off;
    size_t rem = (ws_size > off) ? (ws_size - off) : 0;

    long long nc = (long long)((rem / ((size_t)B_ * 4)) & ~(size_t)127);
    long long ncMax = ((N_ + 127) / 128) * 128;
    if (nc > ncMax) nc = ncMax;
    if (nc < 128) nc = 128;
    int Nc0 = (int)nc;
    long long bcq = (long long)(rem / ((size_t)K_ * H_ * 2 * 2));
    if (bcq > B_) bcq = B_;
    if (bcq < 1) bcq = 1;
    int Bc = (int)bcq;

    // stage 0: combined candidate weights + transposed bf16 weights
    {
        dim3 g(H_ / 64, D_ / 64);
        gemm_nn<0><<<g, 256, 0, stream>>>(W_enc, W_key, nullptr, Wc, D_, H_, H_);
        bcomb_k<<<(H_ + 255) / 256, 256, 0, stream>>>(b_enc, W_key, b_key, bc);
        dim3 gt1((H_ + 31) / 32, (D_ + 31) / 32);
        transpose_f2b<<<gt1, 256, 0, stream>>>(Wc, WcT, D_, H_);
        dim3 gt2((H_ + 31) / 32, (H_ + 31) / 32);
        transpose_f2b<<<gt2, 256, 0, stream>>>(W_t1, Wt1T, H_, H_);
        transpose_f2b<<<gt2, 256, 0, stream>>>(W_t2, Wt2T, H_, H_);
    }
    // stage 1: query encodes (fp32, tiny) + bf16 conversions
    {
        dim3 gx(H_ / 64, B_ / 64);
        gemm_nn<0><<<gx, 256, 0, stream>>>(x, W_enc, b_enc, xe, B_, H_, D_);
        gemm_nn<0><<<gx, 256, 0, stream>>>(x, Wc, bc, xk, B_, H_, D_);
        conv_f2b<<<1024, 256, 0, stream>>>(xk, xkb, B_ * H_);
        conv_f2b<<<2048, 256, 0, stream>>>(cx, cxb, N_ * D_);
    }
    // stage 2: candidate keys via bf16 MFMA (bias, no relu)
    {
        dim3 g(H_ / 128, (N_ + 127) / 128);
        gemm_nt<3><<<g, 256, 0, stream>>>(cxb, WcT, bc, nullptr, nullptr, ckb,
                                          N_, H_, D_, H_, H_);
    }
    rowsq_b<<<N_, 64, 0, stream>>>(ckb, c2);
    rowsq_b<<<B_, 64, 0, stream>>>(xkb, q2);

    // stage 3: chunked sim MFMA GEMM + streaming top-k
    topk_init<<<(B_ * K_ + 255) / 256, 256, 0, stream>>>(topV, topI, thr);
    float* simBuf = (float*)big;
    for (int j0 = 0; j0 < N_; j0 += Nc0) {
        int ncols = min(Nc0, N_ - j0);
        dim3 g((ncols + 127) / 128, B_ / 128);
        gemm_nt<2><<<g, 256, 0, stream>>>(xkb, ckb + (size_t)j0 * H_, nullptr,
                                          q2, c2 + j0, simBuf,
                                          B_, N_ - j0, H_, Nc0, ncols);
        topk_merge<<<B_, 256, 0, stream>>>(simBuf, Nc0, ncols, j0, topV, topI, thr);
    }
    softmax_k<<<B_, 128, 0, stream>>>(topV, attn);

    // stage 4: correction MLP (bf16 MFMA) + weighted reduce
    ushort* diffB = (ushort*)big;
    ushort* hB = (ushort*)(big + (size_t)Bc * K_ * H_ * 2);
    for (int b0 = 0; b0 < B_; b0 += Bc) {
        int bcn = min(Bc, B_ - b0);
        int Mrows = bcn * K_;
        gather_diff_b<<<Mrows, 128, 0, stream>>>(xk, ckb, topI, diffB, b0);
        dim3 g1(H_ / 128, (Mrows + 127) / 128);
        gemm_nt<1><<<g1, 256, 0, stream>>>(diffB, Wt1T, b_t1, nullptr, nullptr,
                                           hB, Mrows, H_, H_, H_, H_);
        gemm_nt<0><<<g1, 256, 0, stream>>>(hB, Wt2T, nullptr, nullptr, nullptr,
                                           diffB, Mrows, H_, H_, H_, H_);
        reduce_ctx<<<bcn, 256, 0, stream>>>(attn, topI, labels, E_label,
                                            diffB, xe, out, b0);
    }
}